// Round 2
// baseline (387.068 us; speedup 1.0000x reference)
//
#include <hip/hip_runtime.h>

#define N_NODES 100000
#define D_FEAT 128
#define N_CLASSES 32
#define SCAN_CHUNK 2048  // 256 threads * 8 elems

// ---------- projection: y = x @ W^T, 4 nodes per thread ----------
// thread -> (node-quad, class); 32 consecutive lanes share the quad.
__global__ __launch_bounds__(256) void gin_project4(
    const float* __restrict__ x, const float* __restrict__ W,
    float* __restrict__ y, int n_quads) {
  __shared__ float Wt[D_FEAT * N_CLASSES];  // Wt[d*32+c] = W[c*128+d]
  int tid = threadIdx.x;
  for (int i = tid; i < D_FEAT * N_CLASSES; i += 256) {
    int c = i >> 7, d = i & 127;
    Wt[d * N_CLASSES + c] = W[i];
  }
  __syncthreads();

  int gid = blockIdx.x * 256 + tid;
  int q = gid >> 5, c = gid & 31;
  if (q >= n_quads) return;
  int n0 = q * 4;
  const float4* x4 = (const float4*)x;
  float a0 = 0.f, a1 = 0.f, a2 = 0.f, a3 = 0.f;
#pragma unroll 4
  for (int d4 = 0; d4 < D_FEAT / 4; ++d4) {
    float4 xv0 = x4[(size_t)(n0 + 0) * 32 + d4];  // broadcast within group
    float4 xv1 = x4[(size_t)(n0 + 1) * 32 + d4];
    float4 xv2 = x4[(size_t)(n0 + 2) * 32 + d4];
    float4 xv3 = x4[(size_t)(n0 + 3) * 32 + d4];
    int base = d4 * 4 * N_CLASSES + c;
    float w0 = Wt[base], w1 = Wt[base + 32], w2 = Wt[base + 64], w3 = Wt[base + 96];
    a0 += xv0.x * w0 + xv0.y * w1 + xv0.z * w2 + xv0.w * w3;
    a1 += xv1.x * w0 + xv1.y * w1 + xv1.z * w2 + xv1.w * w3;
    a2 += xv2.x * w0 + xv2.y * w1 + xv2.z * w2 + xv2.w * w3;
    a3 += xv3.x * w0 + xv3.y * w1 + xv3.z * w2 + xv3.w * w3;
  }
  y[(size_t)(n0 + 0) * 32 + c] = a0;
  y[(size_t)(n0 + 1) * 32 + c] = a1;
  y[(size_t)(n0 + 2) * 32 + c] = a2;
  y[(size_t)(n0 + 3) * 32 + c] = a3;
}

// ---------- CSR build ----------
__global__ void gin_hist(const int* __restrict__ dst, int* __restrict__ off, int E) {
  int e = blockIdx.x * 256 + threadIdx.x;
  if (e < E) atomicAdd(&off[dst[e]], 1);
}

// in-place exclusive scan, stage 1: per-block (2048 elems)
__global__ __launch_bounds__(256) void gin_scan1(int* __restrict__ off,
                                                 int* __restrict__ bsum, int n) {
  __shared__ int s[256];
  int tid = threadIdx.x;
  int base = blockIdx.x * SCAN_CHUNK + tid * 8;
  int v[8];
  int sum = 0;
#pragma unroll
  for (int j = 0; j < 8; ++j) {
    v[j] = (base + j < n) ? off[base + j] : 0;
    sum += v[j];
  }
  s[tid] = sum;
  __syncthreads();
  for (int o = 1; o < 256; o <<= 1) {
    int t = (tid >= o) ? s[tid - o] : 0;
    __syncthreads();
    s[tid] += t;
    __syncthreads();
  }
  int excl = s[tid] - sum;
#pragma unroll
  for (int j = 0; j < 8; ++j) {
    if (base + j < n) off[base + j] = excl;
    excl += v[j];
  }
  if (tid == 255) bsum[blockIdx.x] = s[255];
}

// stage 2: scan the block sums (nb <= 64), also write off[n] = total
__global__ __launch_bounds__(64) void gin_scan2(int* __restrict__ bsum,
                                                int* __restrict__ off, int nb, int n) {
  __shared__ int s[64];
  int tid = threadIdx.x;
  int v = (tid < nb) ? bsum[tid] : 0;
  s[tid] = v;
  __syncthreads();
  for (int o = 1; o < 64; o <<= 1) {
    int t = (tid >= o) ? s[tid - o] : 0;
    __syncthreads();
    s[tid] += t;
    __syncthreads();
  }
  if (tid < nb) bsum[tid] = s[tid] - v;  // exclusive block offset
  if (tid == 63) off[n] = s[63];         // total edge count
}

// stage 3: add block offsets
__global__ void gin_scan3(int* __restrict__ off, const int* __restrict__ bsum, int n) {
  int i = blockIdx.x * 256 + threadIdx.x;
  if (i < n) off[i] += bsum[i >> 11];  // SCAN_CHUNK == 2048
}

// place src ids into CSR bins
__global__ void gin_place(const int* __restrict__ src, const int* __restrict__ dst,
                          int* __restrict__ cursor, int* __restrict__ csr, int E) {
  int e = blockIdx.x * 256 + threadIdx.x;
  if (e >= E) return;
  int d = dst[e];
  int p = atomicAdd(&cursor[d], 1);
  csr[p] = src[e];
}

// ---------- gather: out[n][c] = y[n][c] + sum_in-edges y[s][c] + b[c] ----------
__global__ __launch_bounds__(256) void gin_gather(
    const int* __restrict__ off, const int* __restrict__ csr,
    const float* __restrict__ y, const float* __restrict__ b,
    float* __restrict__ out) {
  int gid = blockIdx.x * 256 + threadIdx.x;
  int n = gid >> 5, c = gid & 31;
  if (n >= N_NODES) return;
  int i = off[n], end = off[n + 1];
  float acc = y[(size_t)n * N_CLASSES + c];
  for (; i + 4 <= end; i += 4) {
    int s0 = csr[i], s1 = csr[i + 1], s2 = csr[i + 2], s3 = csr[i + 3];
    float v0 = y[(size_t)s0 * N_CLASSES + c];
    float v1 = y[(size_t)s1 * N_CLASSES + c];
    float v2 = y[(size_t)s2 * N_CLASSES + c];
    float v3 = y[(size_t)s3 * N_CLASSES + c];
    acc += v0 + v1 + v2 + v3;
  }
  for (; i < end; ++i) acc += y[(size_t)csr[i] * N_CLASSES + c];
  out[(size_t)n * N_CLASSES + c] = acc + b[c];
}

// ---------- fallback (round-1 path) if ws too small ----------
__global__ __launch_bounds__(256) void gin_project_fb(
    const float* __restrict__ x, const float* __restrict__ W,
    const float* __restrict__ b, float* __restrict__ y, float* __restrict__ out) {
  __shared__ float Wt[D_FEAT * N_CLASSES];
  __shared__ float bs[N_CLASSES];
  int tid = threadIdx.x;
  for (int i = tid; i < D_FEAT * N_CLASSES; i += 256) {
    int c = i >> 7, d = i & 127;
    Wt[d * N_CLASSES + c] = W[i];
  }
  if (tid < N_CLASSES) bs[tid] = b[tid];
  __syncthreads();
  int gid = blockIdx.x * 256 + tid;
  int n = gid >> 5, c = gid & 31;
  if (n >= N_NODES) return;
  const float4* xr = (const float4*)(x + (size_t)n * D_FEAT);
  float acc = 0.f;
#pragma unroll 8
  for (int d4 = 0; d4 < D_FEAT / 4; ++d4) {
    float4 xv = xr[d4];
    int base = d4 * 4 * N_CLASSES + c;
    acc += xv.x * Wt[base] + xv.y * Wt[base + N_CLASSES] +
           xv.z * Wt[base + 2 * N_CLASSES] + xv.w * Wt[base + 3 * N_CLASSES];
  }
  size_t o = (size_t)n * N_CLASSES + c;
  y[o] = acc;
  out[o] = acc + bs[c];
}

__global__ __launch_bounds__(256) void gin_scatter_fb(
    const int* __restrict__ src, const int* __restrict__ dst,
    const float* __restrict__ y, float* __restrict__ out, int n_edges) {
  long long gid = (long long)blockIdx.x * 256 + threadIdx.x;
  int e = (int)(gid >> 5);
  int c = (int)(gid & 31);
  if (e >= n_edges) return;
  int s = src[e];
  int d = dst[e];
  atomicAdd(&out[(size_t)d * N_CLASSES + c], y[(size_t)s * N_CLASSES + c]);
}

extern "C" void kernel_launch(void* const* d_in, const int* in_sizes, int n_in,
                              void* d_out, int out_size, void* d_ws, size_t ws_size,
                              hipStream_t stream) {
  const float* x = (const float*)d_in[0];
  const int* edge_index = (const int*)d_in[1];
  const float* W = (const float*)d_in[2];
  const float* b = (const float*)d_in[3];
  float* out = (float*)d_out;

  int E = in_sizes[1] / 2;
  const int* src = edge_index;
  const int* dst = edge_index + E;

  // workspace layout (16B aligned)
  char* ws = (char*)d_ws;
  size_t sz_y = (size_t)N_NODES * N_CLASSES * 4;       // 12,800,000
  size_t sz_off = ((size_t)(N_NODES + 1) * 4 + 15) & ~15ull;  // 400,016
  size_t sz_bsum = 256;
  size_t sz_csr = (size_t)E * 4;

  float* y = (float*)ws;
  int* off = (int*)(ws + sz_y);
  int* cursor = (int*)(ws + sz_y + sz_off);
  int* bsum = (int*)(ws + sz_y + 2 * sz_off);
  int* csr = (int*)(ws + sz_y + 2 * sz_off + sz_bsum);
  size_t need = sz_y + 2 * sz_off + sz_bsum + sz_csr;

  if (ws_size < need) {
    // fallback: round-1 atomic path
    int threads1 = N_NODES * N_CLASSES;
    gin_project_fb<<<(threads1 + 255) / 256, 256, 0, stream>>>(x, W, b, y, out);
    long long threads2 = (long long)E * N_CLASSES;
    gin_scatter_fb<<<(int)((threads2 + 255) / 256), 256, 0, stream>>>(src, dst, y, out, E);
    return;
  }

  // 1) projection into y
  int n_quads = N_NODES / 4;  // 25000 exact
  gin_project4<<<(n_quads * 32 + 255) / 256, 256, 0, stream>>>(x, W, y, n_quads);

  // 2) CSR build: histogram -> exclusive scan (in-place) -> place
  hipMemsetAsync(off, 0, (size_t)(N_NODES + 1) * 4, stream);
  gin_hist<<<(E + 255) / 256, 256, 0, stream>>>(dst, off, E);
  int nb = (N_NODES + SCAN_CHUNK - 1) / SCAN_CHUNK;  // 49
  gin_scan1<<<nb, 256, 0, stream>>>(off, bsum, N_NODES);
  gin_scan2<<<1, 64, 0, stream>>>(bsum, off, nb, N_NODES);
  gin_scan3<<<(N_NODES + 255) / 256, 256, 0, stream>>>(off, bsum, N_NODES);
  hipMemcpyAsync(cursor, off, (size_t)(N_NODES + 1) * 4, hipMemcpyDeviceToDevice, stream);
  gin_place<<<(E + 255) / 256, 256, 0, stream>>>(src, dst, cursor, csr, E);

  // 3) gather + bias into out
  gin_gather<<<(N_NODES * N_CLASSES + 255) / 256, 256, 0, stream>>>(off, csr, y, b, out);
}